// Round 6
// baseline (43.457 us; speedup 1.0000x reference)
//
#include <hip/hip_runtime.h>

// NQ=8, NL=3, B=65536 — fully fused single kernel.
// Per block (256 thr, 256 samples): redundantly build the sample-independent
// quadratic form, then evaluate its samples.
//   psi0_k = v0^8 * t^popcount(k), t = tan(a1/2) e^{i a2}  (rank-9 structure)
//   C = U*P (256x9, thread j holds row j = Cv[9]); final diag of U cancels.
//   P_i(j) = products {|C_jm|^2, 2 C_j,k+d conj(C_jk)} (81 reals per thread)
//   G^q_i  = sum_j (-1)^{bit_{7-q}(j)} P_i(j)  ==  singleton Walsh coeffs of P
//            -> distributed in-place WHT over thread index j (6 shuffle levels
//               in-wave + cross-wave combine through LDS).
//   out_q  = q1^8 * [A^q(u) + sum_d Re(t^d) ReB^q_d(u) - Im(t^d) ImB^q_d(u)]

template <int CTRL>
__device__ __forceinline__ float dppf(float x) {
    return __int_as_float(
        __builtin_amdgcn_mov_dpp(__float_as_int(x), CTRL, 0xF, 0xF, true));
}
template <int PAT>
__device__ __forceinline__ float swzp(float x) {
    return __int_as_float(__builtin_amdgcn_ds_swizzle(__float_as_int(x), PAT));
}
// lane ^ (1<<B) exchange, picking the cheapest primitive per bit
template <int B>
__device__ __forceinline__ float lane_xor(float x) {
    if constexpr (B == 0) return dppf<0xB1>(x);        // quad_perm xor1
    else if constexpr (B == 1) return dppf<0x4E>(x);   // quad_perm xor2
    else if constexpr (B == 2) return swzp<0x101F>(x); // ds_swizzle xor4
    else if constexpr (B == 3) return dppf<0x128>(x);  // row_ror:8 == xor8
    else if constexpr (B == 4) return swzp<0x401F>(x); // ds_swizzle xor16
    else return __shfl_xor(x, 32, 64);                 // permlane xor32
}

__device__ __forceinline__ void gate_lds(float2 Cv[9], float2 (*xch)[256],
                                         float2 cs, int t, int mask) {
    __syncthreads();                       // prior xch readers done
    #pragma unroll
    for (int m = 0; m < 9; ++m) xch[m][t] = Cv[m];
    __syncthreads();
    float2 P[9];
    #pragma unroll
    for (int m = 0; m < 9; ++m) P[m] = xch[m][t ^ mask];
    const float sg = (t & mask) ? cs.y : -cs.y;
    #pragma unroll
    for (int m = 0; m < 9; ++m) {
        Cv[m].x = cs.x * Cv[m].x + sg * P[m].x;
        Cv[m].y = cs.x * Cv[m].y + sg * P[m].y;
    }
}

template <int B>
__device__ __forceinline__ void gate_wave(float2 Cv[9], float2 cs, int t) {
    const float sg = ((t >> B) & 1) ? cs.y : -cs.y;
    #pragma unroll
    for (int m = 0; m < 9; ++m) {
        const float pr = lane_xor<B>(Cv[m].x);
        const float pi = lane_xor<B>(Cv[m].y);
        Cv[m].x = cs.x * Cv[m].x + sg * pr;
        Cv[m].y = cs.x * Cv[m].y + sg * pi;
    }
}

__global__ __launch_bounds__(256, 1)
void qsim_fused(const float* __restrict__ w, const float* __restrict__ z1,
                const float* __restrict__ z2, float* __restrict__ out,
                int nsamp) {
    __shared__ float2 xch[9][256];   // 18 KB: gate exchange; reused as WHT buf
    __shared__ float2 s_cs[3][8];    // (cos, sin) of weights[l][q]/2
    __shared__ float g[8 * 84];      // G coefficients, 84-padded rows

    const int t = threadIdx.x;
    const int lane = t & 63, wv = t >> 6;

    if (t < 24) {
        int l = t >> 3, q = t & 7;
        float a = 0.5f * w[l * 15 + q];
        s_cs[l][q] = make_float2(__cosf(a), __sinf(a));
    }
    __syncthreads();

    // ---- phase A: evolve the 9 popcount-class columns; thread = basis j = t
    float2 Cv[9];
    #pragma unroll
    for (int m = 0; m < 9; ++m)
        Cv[m] = make_float2((__popc(t) == m) ? 1.f : 0.f, 0.f);

    for (int l = 0; l < 3; ++l) {
        gate_lds(Cv, xch, s_cs[l][0], t, 128);   // wire 0 <-> bit 7
        gate_lds(Cv, xch, s_cs[l][1], t, 64);    // wire 1 <-> bit 6
        gate_wave<5>(Cv, s_cs[l][2], t);
        gate_wave<4>(Cv, s_cs[l][3], t);
        gate_wave<3>(Cv, s_cs[l][4], t);
        gate_wave<2>(Cv, s_cs[l][5], t);
        gate_wave<1>(Cv, s_cs[l][6], t);
        gate_wave<0>(Cv, s_cs[l][7], t);
        if (l < 2) {                              // RZZ diag (last one cancels)
            float ang = 0.f;
            #pragma unroll
            for (int i = 0; i < 7; ++i) {
                float zz = (((t >> (7 - i)) ^ (t >> (6 - i))) & 1) ? -1.f : 1.f;
                ang = fmaf(w[l * 15 + 8 + i], zz, ang);
            }
            float s2, c2;
            __sincosf(0.5f * ang, &s2, &c2);      // amp *= exp(-0.5 i ang)
            #pragma unroll
            for (int m = 0; m < 9; ++m) {
                const float nr = Cv[m].x * c2 + Cv[m].y * s2;
                const float ni = Cv[m].y * c2 - Cv[m].x * s2;
                Cv[m].x = nr; Cv[m].y = ni;
            }
        }
    }

    // ---- phase B: per-thread quadratic products, then distributed WHT
    float v[81];
    #pragma unroll
    for (int m = 0; m < 9; ++m)
        v[m] = Cv[m].x * Cv[m].x + Cv[m].y * Cv[m].y;
    {
        int idx = 9;
        #pragma unroll
        for (int d = 1; d <= 8; ++d) {
            #pragma unroll
            for (int k = 0; k + d <= 8; ++k) {
                const float2 hi = Cv[k + d], lo = Cv[k];   // 2 * hi * conj(lo)
                v[idx++] = 2.f * (hi.x * lo.x + hi.y * lo.y);
                v[idx++] = 2.f * (hi.y * lo.x - hi.x * lo.y);
            }
        }
    }
    // in-wave WHT over lane bits 0..5: v_j <- sum_k (-1)^{popc(L&k)} P(k)
    {
        #define WHT_LEVEL(B)                                             \
        {                                                                \
            const float sgn = ((lane >> (B)) & 1) ? -1.f : 1.f;          \
            _Pragma("unroll")                                            \
            for (int i = 0; i < 81; ++i) {                               \
                const float p = lane_xor<B>(v[i]);                       \
                v[i] = fmaf(sgn, v[i], p);                               \
            }                                                            \
        }
        WHT_LEVEL(0) WHT_LEVEL(1) WHT_LEVEL(2)
        WHT_LEVEL(3) WHT_LEVEL(4) WHT_LEVEL(5)
        #undef WHT_LEVEL
    }
    // cross-wave combine: wave w's lanes {0,1,2,4,8,16,32} hold the needed
    // in-wave Walsh rows; stage them in LDS (reuse xch), combine over w.
    float* buf = (float*)xch;        // 4 waves * 7 rows * 81 floats = 9072 B
    __syncthreads();                 // phase-A xch readers all done
    {
        const int row = (lane == 0) ? 0 : (lane == 1) ? 1 : (lane == 2) ? 2 :
                        (lane == 4) ? 3 : (lane == 8) ? 4 : (lane == 16) ? 5 :
                        (lane == 32) ? 6 : -1;
        if (row >= 0) {
            #pragma unroll
            for (int i = 0; i < 81; ++i) buf[(wv * 7 + row) * 81 + i] = v[i];
        }
    }
    __syncthreads();
    for (int o = t; o < 648; o += 256) {
        const int q = o / 81, i = o - 81 * q;
        const int b = 7 - q;                      // qubit q <-> idx bit 7-q
        float r;
        if (b < 6) {                              // Walsh index 2^b: all waves +
            const int rw = b + 1;
            r = buf[(0 * 7 + rw) * 81 + i] + buf[(1 * 7 + rw) * 81 + i] +
                buf[(2 * 7 + rw) * 81 + i] + buf[(3 * 7 + rw) * 81 + i];
        } else if (b == 6) {                      // sign = (-1)^{bit0(wave)}
            r = buf[(0 * 7) * 81 + i] - buf[(1 * 7) * 81 + i] +
                buf[(2 * 7) * 81 + i] - buf[(3 * 7) * 81 + i];
        } else {                                  // sign = (-1)^{bit1(wave)}
            r = buf[(0 * 7) * 81 + i] + buf[(1 * 7) * 81 + i] -
                buf[(2 * 7) * 81 + i] - buf[(3 * 7) * 81 + i];
        }
        g[q * 84 + i] = r;
    }
    __syncthreads();

    // ---- phase C: evaluate one sample per thread
    const int s = blockIdx.x * 256 + t;
    if (s >= nsamp) return;

    const float z1v = z1[s], z2v = z2[s];
    const float u1 = sqrtf(fmaxf(0.f, 1.f - z1v * z1v));   // cos a1
    const float q1 = 0.5f * (1.f + u1);                     // cos^2(a1/2)
    const float s1 = copysignf(sqrtf(fmaxf(0.f, 0.5f * (1.f - u1))), z1v);
    const float tn = s1 * rsqrtf(q1);                       // tan(a1/2)
    const float u2 = sqrtf(fmaxf(0.f, 1.f - z2v * z2v));    // cos a2
    const float tr = tn * u2, ti = tn * z2v;                // t = tn e^{i a2}
    const float u  = tn * tn;                               // |t|^2
    float w8 = q1 * q1; w8 *= w8; w8 *= w8;                 // q1^8

    float Tr[9], Ti[9];
    Tr[1] = tr; Ti[1] = ti;
    #pragma unroll
    for (int d = 2; d <= 8; ++d) {
        Tr[d] = Tr[d - 1] * tr - Ti[d - 1] * ti;
        Ti[d] = Tr[d - 1] * ti + Ti[d - 1] * tr;
    }

    float o[8];
    #pragma unroll
    for (int q = 0; q < 8; ++q) {
        const float* gq = g + q * 84;            // LDS, broadcast reads
        float r = gq[8];
        #pragma unroll
        for (int m = 7; m >= 0; --m) r = fmaf(r, u, gq[m]);
        int off = 9;
        #pragma unroll
        for (int d = 1; d <= 8; ++d) {
            const int K = 8 - d;                 // poly degree in u
            float br = gq[off + 2 * K], bi = gq[off + 2 * K + 1];
            #pragma unroll
            for (int k = K - 1; k >= 0; --k) {
                br = fmaf(br, u, gq[off + 2 * k]);
                bi = fmaf(bi, u, gq[off + 2 * k + 1]);
            }
            r = fmaf(Tr[d], br, r);
            r = fmaf(-Ti[d], bi, r);
            off += 2 * (K + 1);
        }
        o[q] = w8 * r;
    }

    float4* op = (float4*)(out + (size_t)s * 8);
    op[0] = make_float4(o[0], o[1], o[2], o[3]);
    op[1] = make_float4(o[4], o[5], o[6], o[7]);
}

extern "C" void kernel_launch(void* const* d_in, const int* in_sizes, int n_in,
                              void* d_out, int out_size, void* d_ws,
                              size_t ws_size, hipStream_t stream) {
    const float* w  = (const float*)d_in[0];   // (3, 15) f32
    const float* z1 = (const float*)d_in[1];   // (B,)   f32
    const float* z2 = (const float*)d_in[2];   // (B,)   f32
    float* out = (float*)d_out;                // (B, 8) f32

    const int n = in_sizes[1];
    qsim_fused<<<(n + 255) / 256, 256, 0, stream>>>(w, z1, z2, out, n);
}

// Round 7
// 19.062 us; speedup vs baseline: 2.2798x; 2.2798x over previous
//
#include <hip/hip_runtime.h>

// NQ=8, NL=3, B=65536 — fully fused single kernel, chunked-WHT edition.
// Per block (256 thr, 256 samples): redundantly build the sample-independent
// quadratic form, then evaluate its samples.
//   psi0_k = v0^8 * t^popcount(k), t = tan(a1/2) e^{i a2}  (rank-9 structure)
//   C = U*P (256x9, thread j holds row j = Cv[9]); final diag of U cancels.
//   P_i(j) = products {|C_jm|^2, 2 C_j,k+d conj(C_jk)} (81 reals per thread)
//   G^q_i  = sum_j (-1)^{bit_{7-q}(j)} P_i(j)  ==  singleton Walsh coeffs of P
//            -> WHT over thread index, processed in <=16-float CHUNKS so the
//               live set stays ~50 VGPRs (R5's 81-float version spilled 90MB).
//   out_q  = q1^8 * [A^q(u) + sum_d Re(t^d) ReB^q_d(u) - Im(t^d) ImB^q_d(u)]

template <int CTRL>
__device__ __forceinline__ float dppf(float x) {
    return __int_as_float(
        __builtin_amdgcn_mov_dpp(__float_as_int(x), CTRL, 0xF, 0xF, true));
}
template <int PAT>
__device__ __forceinline__ float swzp(float x) {
    return __int_as_float(__builtin_amdgcn_ds_swizzle(__float_as_int(x), PAT));
}
// lane ^ (1<<B) exchange, cheapest primitive per bit
template <int B>
__device__ __forceinline__ float lane_xor(float x) {
    if constexpr (B == 0) return dppf<0xB1>(x);        // quad_perm xor1
    else if constexpr (B == 1) return dppf<0x4E>(x);   // quad_perm xor2
    else if constexpr (B == 2) return swzp<0x101F>(x); // ds_swizzle xor4
    else if constexpr (B == 3) return dppf<0x128>(x);  // row_ror:8 == xor8
    else if constexpr (B == 4) return swzp<0x401F>(x); // ds_swizzle xor16
    else return __shfl_xor(x, 32, 64);                 // permlane xor32
}

__device__ __forceinline__ void gate_lds(float2 Cv[9], float2 (*xch)[256],
                                         float2 cs, int t, int mask) {
    __syncthreads();                       // prior xch readers done
    #pragma unroll
    for (int m = 0; m < 9; ++m) xch[m][t] = Cv[m];
    __syncthreads();
    float2 P[9];
    #pragma unroll
    for (int m = 0; m < 9; ++m) P[m] = xch[m][t ^ mask];
    const float sg = (t & mask) ? cs.y : -cs.y;
    #pragma unroll
    for (int m = 0; m < 9; ++m) {
        Cv[m].x = cs.x * Cv[m].x + sg * P[m].x;
        Cv[m].y = cs.x * Cv[m].y + sg * P[m].y;
    }
}

template <int B>
__device__ __forceinline__ void gate_wave(float2 Cv[9], float2 cs, int t) {
    const float sg = ((t >> B) & 1) ? cs.y : -cs.y;
    #pragma unroll
    for (int m = 0; m < 9; ++m) {
        const float pr = lane_xor<B>(Cv[m].x);
        const float pi = lane_xor<B>(Cv[m].y);
        Cv[m].x = cs.x * Cv[m].x + sg * pr;
        Cv[m].y = cs.x * Cv[m].y + sg * pi;
    }
}

// 6-level in-wave WHT of an N-float chunk, then store the 7 needed Walsh
// rows (this wave's lanes 0,1,2,4,8,16,32) at buf[(wv*7+row)*81 + base + i].
template <int N>
__device__ __forceinline__ void wht_chunk(float (&v)[N], float* buf,
                                          int lane, int wv, int row, int base) {
    #define WHT_LVL(B)                                                   \
    {                                                                    \
        const float sgn = ((lane >> (B)) & 1) ? -1.f : 1.f;              \
        _Pragma("unroll")                                                \
        for (int i = 0; i < N; ++i) {                                    \
            const float p = lane_xor<B>(v[i]);                           \
            v[i] = fmaf(sgn, v[i], p);                                   \
        }                                                                \
    }
    WHT_LVL(0) WHT_LVL(1) WHT_LVL(2) WHT_LVL(3) WHT_LVL(4) WHT_LVL(5)
    #undef WHT_LVL
    if (row >= 0) {
        #pragma unroll
        for (int i = 0; i < N; ++i) buf[(wv * 7 + row) * 81 + base + i] = v[i];
    }
}

// products 2 * C_{k+D} * conj(C_k), k = 0..8-D, packed re,im
template <int D, int N>
__device__ __forceinline__ void fill_pairs(const float2 (&Cv)[9], float (&c)[N],
                                           int off) {
    #pragma unroll
    for (int k = 0; k + D <= 8; ++k) {
        const float2 hi = Cv[k + D], lo = Cv[k];
        c[off + 2 * k]     = 2.f * (hi.x * lo.x + hi.y * lo.y);
        c[off + 2 * k + 1] = 2.f * (hi.y * lo.x - hi.x * lo.y);
    }
}

__global__ __launch_bounds__(256, 4)
void qsim_fused(const float* __restrict__ w, const float* __restrict__ z1,
                const float* __restrict__ z2, float* __restrict__ out,
                int nsamp) {
    __shared__ float2 xch[9][256];   // 18 KB: gate exchange; reused as WHT buf
    __shared__ float2 s_cs[3][8];    // (cos, sin) of weights[l][q]/2
    __shared__ float g[8 * 84];      // G coefficients, 84-padded rows

    const int t = threadIdx.x;
    const int lane = t & 63, wv = t >> 6;

    if (t < 24) {
        int l = t >> 3, q = t & 7;
        float a = 0.5f * w[l * 15 + q];
        s_cs[l][q] = make_float2(__cosf(a), __sinf(a));
    }
    __syncthreads();

    // ---- phase A: evolve the 9 popcount-class columns; thread = basis j = t
    float2 Cv[9];
    #pragma unroll
    for (int m = 0; m < 9; ++m)
        Cv[m] = make_float2((__popc(t) == m) ? 1.f : 0.f, 0.f);

    for (int l = 0; l < 3; ++l) {
        gate_lds(Cv, xch, s_cs[l][0], t, 128);   // wire 0 <-> bit 7
        gate_lds(Cv, xch, s_cs[l][1], t, 64);    // wire 1 <-> bit 6
        gate_wave<5>(Cv, s_cs[l][2], t);
        gate_wave<4>(Cv, s_cs[l][3], t);
        gate_wave<3>(Cv, s_cs[l][4], t);
        gate_wave<2>(Cv, s_cs[l][5], t);
        gate_wave<1>(Cv, s_cs[l][6], t);
        gate_wave<0>(Cv, s_cs[l][7], t);
        if (l < 2) {                              // RZZ diag (last one cancels)
            float ang = 0.f;
            #pragma unroll
            for (int i = 0; i < 7; ++i) {
                float zz = (((t >> (7 - i)) ^ (t >> (6 - i))) & 1) ? -1.f : 1.f;
                ang = fmaf(w[l * 15 + 8 + i], zz, ang);
            }
            float s2, c2;
            __sincosf(0.5f * ang, &s2, &c2);      // amp *= exp(-0.5 i ang)
            #pragma unroll
            for (int m = 0; m < 9; ++m) {
                const float nr = Cv[m].x * c2 + Cv[m].y * s2;
                const float ni = Cv[m].y * c2 - Cv[m].x * s2;
                Cv[m].x = nr; Cv[m].y = ni;
            }
        }
    }

    // ---- phase B: chunked products + distributed WHT
    float* buf = (float*)xch;        // 4 waves * 7 rows * 81 floats = 9072 B
    __syncthreads();                 // phase-A xch readers all done
    const int row = (lane == 0) ? 0 : (lane == 1) ? 1 : (lane == 2) ? 2 :
                    (lane == 4) ? 3 : (lane == 8) ? 4 : (lane == 16) ? 5 :
                    (lane == 32) ? 6 : -1;
    {   // diag |C_m|^2  -> components 0..8
        float c[9];
        #pragma unroll
        for (int m = 0; m < 9; ++m)
            c[m] = Cv[m].x * Cv[m].x + Cv[m].y * Cv[m].y;
        wht_chunk(c, buf, lane, wv, row, 0);
    }
    { float c[16]; fill_pairs<1>(Cv, c, 0); wht_chunk(c, buf, lane, wv, row, 9);  }
    { float c[14]; fill_pairs<2>(Cv, c, 0); wht_chunk(c, buf, lane, wv, row, 25); }
    { float c[12]; fill_pairs<3>(Cv, c, 0); wht_chunk(c, buf, lane, wv, row, 39); }
    { float c[10]; fill_pairs<4>(Cv, c, 0); wht_chunk(c, buf, lane, wv, row, 51); }
    { float c[8];  fill_pairs<5>(Cv, c, 0); wht_chunk(c, buf, lane, wv, row, 61); }
    {   // d = 6,7,8 combined -> components 69..80
        float c[12];
        fill_pairs<6>(Cv, c, 0);
        fill_pairs<7>(Cv, c, 6);
        fill_pairs<8>(Cv, c, 10);
        wht_chunk(c, buf, lane, wv, row, 69);
    }
    __syncthreads();
    // cross-wave combine; qubit q <-> idx bit b = 7-q
    for (int o = t; o < 648; o += 256) {
        const int q = o / 81, i = o - 81 * q;
        const int b = 7 - q;
        float r;
        if (b < 6) {                              // Walsh index 2^b: all waves +
            const int rw = b + 1;
            r = buf[(0 * 7 + rw) * 81 + i] + buf[(1 * 7 + rw) * 81 + i] +
                buf[(2 * 7 + rw) * 81 + i] + buf[(3 * 7 + rw) * 81 + i];
        } else if (b == 6) {                      // sign = (-1)^{bit0(wave)}
            r = buf[(0 * 7) * 81 + i] - buf[(1 * 7) * 81 + i] +
                buf[(2 * 7) * 81 + i] - buf[(3 * 7) * 81 + i];
        } else {                                  // sign = (-1)^{bit1(wave)}
            r = buf[(0 * 7) * 81 + i] + buf[(1 * 7) * 81 + i] -
                buf[(2 * 7) * 81 + i] - buf[(3 * 7) * 81 + i];
        }
        g[q * 84 + i] = r;
    }
    __syncthreads();

    // ---- phase C: evaluate one sample per thread
    const int s = blockIdx.x * 256 + t;
    if (s >= nsamp) return;

    const float z1v = z1[s], z2v = z2[s];
    const float u1 = sqrtf(fmaxf(0.f, 1.f - z1v * z1v));   // cos a1
    const float q1 = 0.5f * (1.f + u1);                     // cos^2(a1/2)
    const float s1 = copysignf(sqrtf(fmaxf(0.f, 0.5f * (1.f - u1))), z1v);
    const float tn = s1 * rsqrtf(q1);                       // tan(a1/2)
    const float u2 = sqrtf(fmaxf(0.f, 1.f - z2v * z2v));    // cos a2
    const float tr = tn * u2, ti = tn * z2v;                // t = tn e^{i a2}
    const float u  = tn * tn;                               // |t|^2
    float w8 = q1 * q1; w8 *= w8; w8 *= w8;                 // q1^8

    float Tr[9], Ti[9];
    Tr[1] = tr; Ti[1] = ti;
    #pragma unroll
    for (int d = 2; d <= 8; ++d) {
        Tr[d] = Tr[d - 1] * tr - Ti[d - 1] * ti;
        Ti[d] = Tr[d - 1] * ti + Ti[d - 1] * tr;
    }

    float o[8];
    #pragma unroll
    for (int q = 0; q < 8; ++q) {
        const float* gq = g + q * 84;            // LDS, broadcast reads
        float r = gq[8];
        #pragma unroll
        for (int m = 7; m >= 0; --m) r = fmaf(r, u, gq[m]);
        int off = 9;
        #pragma unroll
        for (int d = 1; d <= 8; ++d) {
            const int K = 8 - d;                 // poly degree in u
            float br = gq[off + 2 * K], bi = gq[off + 2 * K + 1];
            #pragma unroll
            for (int k = K - 1; k >= 0; --k) {
                br = fmaf(br, u, gq[off + 2 * k]);
                bi = fmaf(bi, u, gq[off + 2 * k + 1]);
            }
            r = fmaf(Tr[d], br, r);
            r = fmaf(-Ti[d], bi, r);
            off += 2 * (K + 1);
        }
        o[q] = w8 * r;
    }

    float4* op = (float4*)(out + (size_t)s * 8);
    op[0] = make_float4(o[0], o[1], o[2], o[3]);
    op[1] = make_float4(o[4], o[5], o[6], o[7]);
}

extern "C" void kernel_launch(void* const* d_in, const int* in_sizes, int n_in,
                              void* d_out, int out_size, void* d_ws,
                              size_t ws_size, hipStream_t stream) {
    const float* w  = (const float*)d_in[0];   // (3, 15) f32
    const float* z1 = (const float*)d_in[1];   // (B,)   f32
    const float* z2 = (const float*)d_in[2];   // (B,)   f32
    float* out = (float*)d_out;                // (B, 8) f32

    const int n = in_sizes[1];
    qsim_fused<<<(n + 255) / 256, 256, 0, stream>>>(w, z1, z2, out, n);
}